// Round 1
// baseline (622.349 us; speedup 1.0000x reference)
//
#include <hip/hip_runtime.h>

#define IN_DIM 256
#define EMB 128

// ---------------- CSR build kernels ----------------

__global__ __launch_bounds__(256) void zero_i32(int* __restrict__ p, int n) {
    int i = blockIdx.x * 256 + threadIdx.x;
    if (i < n) p[i] = 0;
}

__global__ __launch_bounds__(256) void hist_kernel(const int* __restrict__ dst,
                                                   int* __restrict__ deg, int E) {
    int i = blockIdx.x * 256 + threadIdx.x;
    if (i < E) atomicAdd(&deg[dst[i]], 1);
}

// per-block sums of 1024-element chunks of deg
__global__ __launch_bounds__(256) void scan_reduce(const int* __restrict__ deg,
                                                   int* __restrict__ bsums, int N) {
    __shared__ int s[256];
    int tid = threadIdx.x;
    int base = blockIdx.x * 1024 + tid * 4;
    int t = 0;
#pragma unroll
    for (int j = 0; j < 4; ++j) {
        int idx = base + j;
        if (idx < N) t += deg[idx];
    }
    s[tid] = t;
    __syncthreads();
    for (int off = 128; off > 0; off >>= 1) {
        if (tid < off) s[tid] += s[tid + off];
        __syncthreads();
    }
    if (tid == 0) bsums[blockIdx.x] = s[0];
}

// exclusive scan of block sums (nb <= 128), also writes row_ptr[N]=E
__global__ __launch_bounds__(128) void scan_offsets(int* __restrict__ bsums, int nb,
                                                    int* __restrict__ row_ptr, int N, int E) {
    __shared__ int s[128];
    int tid = threadIdx.x;
    int v = (tid < nb) ? bsums[tid] : 0;
    s[tid] = v;
    __syncthreads();
    for (int off = 1; off < 128; off <<= 1) {
        int t = (tid >= off) ? s[tid - off] : 0;
        __syncthreads();
        s[tid] += t;
        __syncthreads();
    }
    if (tid < nb) bsums[tid] = s[tid] - v;  // exclusive
    if (tid == 0) row_ptr[N] = E;
}

// full exclusive scan of deg -> row_ptr (and cursor copy)
__global__ __launch_bounds__(256) void scan_write(const int* __restrict__ deg,
                                                  const int* __restrict__ bsums,
                                                  int* __restrict__ row_ptr,
                                                  int* __restrict__ cursor, int N) {
    __shared__ int s[256];
    int tid = threadIdx.x;
    int base = blockIdx.x * 1024 + tid * 4;
    int v[4];
    int tsum = 0;
#pragma unroll
    for (int j = 0; j < 4; ++j) {
        int idx = base + j;
        v[j] = (idx < N) ? deg[idx] : 0;
        tsum += v[j];
    }
    s[tid] = tsum;
    __syncthreads();
    for (int off = 1; off < 256; off <<= 1) {
        int t = (tid >= off) ? s[tid - off] : 0;
        __syncthreads();
        s[tid] += t;
        __syncthreads();
    }
    int excl = s[tid] - tsum + bsums[blockIdx.x];
#pragma unroll
    for (int j = 0; j < 4; ++j) {
        int idx = base + j;
        if (idx < N) {
            row_ptr[idx] = excl;
            cursor[idx] = excl;
        }
        excl += v[j];
    }
}

__global__ __launch_bounds__(256) void scatter_kernel(const int* __restrict__ src,
                                                      const int* __restrict__ dst,
                                                      const float* __restrict__ w,
                                                      int* __restrict__ cursor,
                                                      int* __restrict__ srt_src,
                                                      float* __restrict__ srt_w, int E) {
    int i = blockIdx.x * 256 + threadIdx.x;
    if (i < E) {
        int d = dst[i];
        int pos = atomicAdd(&cursor[d], 1);
        srt_src[pos] = src[i];
        srt_w[pos] = w[i];
    }
}

// ---------------- GEMM + bias + relu (f32) ----------------
// block: 64 rows x 128 cols, 256 threads, each thread 8 rows x 4 cols

__global__ __launch_bounds__(256) void gemm_relu(const float* __restrict__ x,
                                                 const float* __restrict__ W,
                                                 const float* __restrict__ b,
                                                 float* __restrict__ out, int N) {
    __shared__ float xs[64][32];
    __shared__ float wsh[32][128];
    int tid = threadIdx.x;
    int tx = tid & 31;   // col group: cols tx*4..tx*4+3
    int ty = tid >> 5;   // row group: rows ty*8..ty*8+7
    int row0 = blockIdx.x * 64;

    float4 bias = ((const float4*)b)[tx];
    float4 acc[8];
#pragma unroll
    for (int i = 0; i < 8; ++i) acc[i] = make_float4(0.f, 0.f, 0.f, 0.f);

    for (int kb = 0; kb < IN_DIM; kb += 32) {
        // stage x tile: 64 rows x 32 floats = 512 float4, 2 per thread
#pragma unroll
        for (int l = 0; l < 2; ++l) {
            int f = tid * 2 + l;
            int r = f >> 3;      // 8 float4 per row
            int c4 = f & 7;
            float4 val = make_float4(0.f, 0.f, 0.f, 0.f);
            if (row0 + r < N)
                val = ((const float4*)(x + (size_t)(row0 + r) * IN_DIM + kb))[c4];
            *((float4*)&xs[r][c4 * 4]) = val;
        }
        // stage W tile: 32 rows x 128 floats = 1024 float4, 4 per thread
#pragma unroll
        for (int l = 0; l < 4; ++l) {
            int f = tid + 256 * l;
            int r = f >> 5;      // 32 float4 per row
            int c4 = f & 31;
            *((float4*)&wsh[r][c4 * 4]) = ((const float4*)(W + (size_t)(kb + r) * EMB))[c4];
        }
        __syncthreads();
#pragma unroll
        for (int kk = 0; kk < 32; ++kk) {
            float4 wv = *((float4*)&wsh[kk][tx * 4]);
#pragma unroll
            for (int i = 0; i < 8; ++i) {
                float xv = xs[ty * 8 + i][kk];
                acc[i].x = fmaf(xv, wv.x, acc[i].x);
                acc[i].y = fmaf(xv, wv.y, acc[i].y);
                acc[i].z = fmaf(xv, wv.z, acc[i].z);
                acc[i].w = fmaf(xv, wv.w, acc[i].w);
            }
        }
        __syncthreads();
    }
#pragma unroll
    for (int i = 0; i < 8; ++i) {
        int r = row0 + ty * 8 + i;
        if (r < N) {
            float4 o;
            o.x = fmaxf(acc[i].x + bias.x, 0.f);
            o.y = fmaxf(acc[i].y + bias.y, 0.f);
            o.z = fmaxf(acc[i].z + bias.z, 0.f);
            o.w = fmaxf(acc[i].w + bias.w, 0.f);
            ((float4*)(out + (size_t)r * EMB))[tx] = o;
        }
    }
}

// ---------------- propagation: one wave per destination node ----------------

__global__ __launch_bounds__(256) void prop_kernel(const float* __restrict__ hin,
                                                   float* __restrict__ hout,
                                                   const int* __restrict__ row_ptr,
                                                   const int* __restrict__ srt_src,
                                                   const float* __restrict__ srt_w, int N) {
    int wave = threadIdx.x >> 6;
    int lane = threadIdx.x & 63;
    int node = blockIdx.x * 4 + wave;
    if (node >= N) return;
    int beg = row_ptr[node];
    int end = row_ptr[node + 1];
    float accx = 0.f, accy = 0.f;
    const float2* h2 = (const float2*)hin;
    for (int e = beg; e < end; ++e) {
        int s = srt_src[e];
        float w = srt_w[e];
        float2 hv = h2[(size_t)s * 64 + lane];
        accx = fmaf(w, hv.x, accx);
        accy = fmaf(w, hv.y, accy);
    }
    float2 o;
    o.x = accx;
    o.y = accy;
    ((float2*)hout)[(size_t)node * 64 + lane] = o;
}

// ---------------- launch ----------------

extern "C" void kernel_launch(void* const* d_in, const int* in_sizes, int n_in,
                              void* d_out, int out_size, void* d_ws, size_t ws_size,
                              hipStream_t stream) {
    const float* x = (const float*)d_in[0];
    const float* W = (const float*)d_in[1];
    const float* b = (const float*)d_in[2];
    const int* esrc = (const int*)d_in[3];
    const int* edst = (const int*)d_in[4];
    const float* ew = (const float*)d_in[5];
    int N = in_sizes[0] / IN_DIM;
    int E = in_sizes[3];

    char* p = (char*)d_ws;
    auto alloc = [&](size_t bytes) -> void* {
        void* r = (void*)p;
        p += (bytes + 255) & ~(size_t)255;
        return r;
    };
    float* h1 = (float*)alloc((size_t)N * EMB * 4);
    int* deg = (int*)alloc((size_t)N * 4);
    int* row_ptr = (int*)alloc((size_t)(N + 1) * 4);
    int* cursor = (int*)alloc((size_t)N * 4);
    int* bsums = (int*)alloc(512);
    int* srt_src = (int*)alloc((size_t)E * 4);
    float* srt_w = (float*)alloc((size_t)E * 4);

    int nscan = (N + 1023) / 1024;  // 98 for N=100000 (must be <=128)

    zero_i32<<<(N + 255) / 256, 256, 0, stream>>>(deg, N);
    hist_kernel<<<(E + 255) / 256, 256, 0, stream>>>(edst, deg, E);
    scan_reduce<<<nscan, 256, 0, stream>>>(deg, bsums, N);
    scan_offsets<<<1, 128, 0, stream>>>(bsums, nscan, row_ptr, N, E);
    scan_write<<<nscan, 256, 0, stream>>>(deg, bsums, row_ptr, cursor, N);
    scatter_kernel<<<(E + 255) / 256, 256, 0, stream>>>(esrc, edst, ew, cursor, srt_src, srt_w, E);

    gemm_relu<<<(N + 63) / 64, 256, 0, stream>>>(x, W, b, (float*)d_out, N);
    prop_kernel<<<(N + 3) / 4, 256, 0, stream>>>((const float*)d_out, h1, row_ptr, srt_src, srt_w, N);
    prop_kernel<<<(N + 3) / 4, 256, 0, stream>>>(h1, (float*)d_out, row_ptr, srt_src, srt_w, N);
}

// Round 2
// 381.047 us; speedup vs baseline: 1.6333x; 1.6333x over previous
//
#include <hip/hip_runtime.h>

#define IN_DIM 256
#define EMB 128

typedef __attribute__((ext_vector_type(8))) short short8;
typedef __attribute__((ext_vector_type(4))) float f32x4;

__device__ __forceinline__ unsigned short bf16rtne(float f) {
    unsigned int u = __float_as_uint(f);
    return (unsigned short)((u + 0x7fffu + ((u >> 16) & 1u)) >> 16);
}

__device__ __forceinline__ unsigned int packbf2(float lo, float hi) {
    return ((unsigned int)bf16rtne(hi) << 16) | (unsigned int)bf16rtne(lo);
}

// ---------------- CSR build kernels ----------------

__global__ __launch_bounds__(256) void hist_kernel(const int* __restrict__ dst,
                                                   int* __restrict__ deg, int E) {
    int i = blockIdx.x * 256 + threadIdx.x;
    if (i < E) atomicAdd(&deg[dst[i]], 1);
}

__global__ __launch_bounds__(256) void scan_reduce(const int* __restrict__ deg,
                                                   int* __restrict__ bsums, int N) {
    __shared__ int s[256];
    int tid = threadIdx.x;
    int base = blockIdx.x * 1024 + tid * 4;
    int t = 0;
#pragma unroll
    for (int j = 0; j < 4; ++j) {
        int idx = base + j;
        if (idx < N) t += deg[idx];
    }
    s[tid] = t;
    __syncthreads();
    for (int off = 128; off > 0; off >>= 1) {
        if (tid < off) s[tid] += s[tid + off];
        __syncthreads();
    }
    if (tid == 0) bsums[blockIdx.x] = s[0];
}

__global__ __launch_bounds__(128) void scan_offsets(int* __restrict__ bsums, int nb,
                                                    int* __restrict__ row_ptr, int N, int E) {
    __shared__ int s[128];
    int tid = threadIdx.x;
    int v = (tid < nb) ? bsums[tid] : 0;
    s[tid] = v;
    __syncthreads();
    for (int off = 1; off < 128; off <<= 1) {
        int t = (tid >= off) ? s[tid - off] : 0;
        __syncthreads();
        s[tid] += t;
        __syncthreads();
    }
    if (tid < nb) bsums[tid] = s[tid] - v;  // exclusive
    if (tid == 0) row_ptr[N] = E;
}

__global__ __launch_bounds__(256) void scan_write(const int* __restrict__ deg,
                                                  const int* __restrict__ bsums,
                                                  int* __restrict__ row_ptr,
                                                  int* __restrict__ cursor, int N) {
    __shared__ int s[256];
    int tid = threadIdx.x;
    int base = blockIdx.x * 1024 + tid * 4;
    int v[4];
    int tsum = 0;
#pragma unroll
    for (int j = 0; j < 4; ++j) {
        int idx = base + j;
        v[j] = (idx < N) ? deg[idx] : 0;
        tsum += v[j];
    }
    s[tid] = tsum;
    __syncthreads();
    for (int off = 1; off < 256; off <<= 1) {
        int t = (tid >= off) ? s[tid - off] : 0;
        __syncthreads();
        s[tid] += t;
        __syncthreads();
    }
    int excl = s[tid] - tsum + bsums[blockIdx.x];
#pragma unroll
    for (int j = 0; j < 4; ++j) {
        int idx = base + j;
        if (idx < N) {
            row_ptr[idx] = excl;
            cursor[idx] = excl;
        }
        excl += v[j];
    }
}

__global__ __launch_bounds__(256) void scatter_kernel(const int* __restrict__ src,
                                                      const int* __restrict__ dst,
                                                      const float* __restrict__ w,
                                                      int* __restrict__ cursor,
                                                      int* __restrict__ srt_src,
                                                      float* __restrict__ srt_w, int E) {
    int i = blockIdx.x * 256 + threadIdx.x;
    if (i < E) {
        int d = dst[i];
        int pos = atomicAdd(&cursor[d], 1);
        srt_src[pos] = src[i];
        srt_w[pos] = w[i];
    }
}

// ---------------- W transpose + cast to bf16: wtg[c][k] = bf16(W[k][c]) ----------------

__global__ __launch_bounds__(256) void wt_cast(const float* __restrict__ W,
                                               unsigned short* __restrict__ wtg) {
    int i = blockIdx.x * 256 + threadIdx.x;  // 32768 total
    int c = i & 127;
    int k = i >> 7;
    wtg[c * 256 + k] = bf16rtne(W[(size_t)k * 128 + c]);
}

// ---------------- MFMA GEMM: h = relu(x@W + b), output bf16 ----------------
// tile 128 rows x 128 cols, BK=64, 4 waves; wave w owns rows w*32..w*32+31.
// LDS XOR-swizzle (elem_off ^= (row&7)<<3) to kill the stride-128B bank conflict.

__global__ __launch_bounds__(256) void gemm_mfma(const float* __restrict__ x,
                                                 const unsigned short* __restrict__ wtg,
                                                 const float* __restrict__ bias,
                                                 unsigned short* __restrict__ hbf, int N) {
    __shared__ unsigned short xs[128][64];
    __shared__ unsigned short wsh[128][64];
    int tid = threadIdx.x;
    int row0 = blockIdx.x * 128;
    int wv = tid >> 6;
    int lane = tid & 63;
    int lr = lane & 15;
    int lg = lane >> 4;
    int wr = wv * 32;

    f32x4 acc[2][8];
#pragma unroll
    for (int m = 0; m < 2; ++m)
#pragma unroll
        for (int n = 0; n < 8; ++n) acc[m][n] = (f32x4){0.f, 0.f, 0.f, 0.f};

    int sr = tid >> 1;   // staging row (x) / col (wt)
    int hh = tid & 1;    // which 32-elem half of the 64-wide K tile
    bool xvalid = (row0 + sr) < N;
    const float* xrow = x + (size_t)(row0 + sr) * IN_DIM + hh * 32;
    const unsigned short* wrow = wtg + (size_t)sr * IN_DIM + hh * 32;

    for (int kb = 0; kb < IN_DIM; kb += 64) {
        // stage x: 32 f32 per thread -> bf16
#pragma unroll
        for (int j = 0; j < 4; ++j) {
            float4 f0 = make_float4(0.f, 0.f, 0.f, 0.f);
            float4 f1 = f0;
            if (xvalid) {
                f0 = ((const float4*)(xrow + kb))[2 * j];
                f1 = ((const float4*)(xrow + kb))[2 * j + 1];
            }
            uint4 pk;
            pk.x = packbf2(f0.x, f0.y);
            pk.y = packbf2(f0.z, f0.w);
            pk.z = packbf2(f1.x, f1.y);
            pk.w = packbf2(f1.z, f1.w);
            int koff = (hh * 32 + j * 8) ^ ((sr & 7) << 3);
            *(uint4*)&xs[sr][koff] = pk;
        }
        // stage W^T (already bf16)
#pragma unroll
        for (int j = 0; j < 4; ++j) {
            uint4 v = ((const uint4*)(wrow + kb))[j];
            int koff = (hh * 32 + j * 8) ^ ((sr & 7) << 3);
            *(uint4*)&wsh[sr][koff] = v;
        }
        __syncthreads();

        short8 a[2][2];
#pragma unroll
        for (int m = 0; m < 2; ++m)
#pragma unroll
            for (int kk = 0; kk < 2; ++kk) {
                int r = wr + m * 16 + lr;
                int koff = (kk * 32 + lg * 8) ^ ((lr & 7) << 3);
                a[m][kk] = *(const short8*)&xs[r][koff];
            }
#pragma unroll
        for (int n = 0; n < 8; ++n) {
            int c = n * 16 + lr;
            int koff0 = (lg * 8) ^ ((lr & 7) << 3);
            int koff1 = (32 + lg * 8) ^ ((lr & 7) << 3);
            short8 b0 = *(const short8*)&wsh[c][koff0];
            short8 b1 = *(const short8*)&wsh[c][koff1];
            acc[0][n] = __builtin_amdgcn_mfma_f32_16x16x32_bf16(a[0][0], b0, acc[0][n], 0, 0, 0);
            acc[0][n] = __builtin_amdgcn_mfma_f32_16x16x32_bf16(a[0][1], b1, acc[0][n], 0, 0, 0);
            acc[1][n] = __builtin_amdgcn_mfma_f32_16x16x32_bf16(a[1][0], b0, acc[1][n], 0, 0, 0);
            acc[1][n] = __builtin_amdgcn_mfma_f32_16x16x32_bf16(a[1][1], b1, acc[1][n], 0, 0, 0);
        }
        __syncthreads();
    }

    // epilogue: bias + relu + bf16 store. C/D: col = lane&15, row = lg*4 + j.
#pragma unroll
    for (int n = 0; n < 8; ++n) {
        int c = n * 16 + lr;
        float bv = bias[c];
#pragma unroll
        for (int m = 0; m < 2; ++m) {
#pragma unroll
            for (int j = 0; j < 4; ++j) {
                int r = row0 + wr + m * 16 + lg * 4 + j;
                if (r < N) {
                    float v = fmaxf(acc[m][n][j] + bv, 0.f);
                    hbf[(size_t)r * EMB + c] = bf16rtne(v);
                }
            }
        }
    }
}

// ---------------- propagation: wave per node, 8-deep gather ILP, bf16 rows ----------------
// hin: bf16 [N][128] viewed as uint [N][64]; lane holds cols {2*lane, 2*lane+1}

template <int OUTBF>
__global__ __launch_bounds__(256) void prop_g(const unsigned int* __restrict__ hin,
                                              void* __restrict__ hout,
                                              const int* __restrict__ rp,
                                              const int* __restrict__ ss,
                                              const float* __restrict__ sw, int N) {
    int wvid = threadIdx.x >> 6;
    int lane = threadIdx.x & 63;
    int node = blockIdx.x * 4 + wvid;
    if (node >= N) return;
    int beg = rp[node];
    int end = rp[node + 1];
    float ax = 0.f, ay = 0.f;
    for (int e = beg; e < end; e += 8) {
        int s[8];
        float w[8];
#pragma unroll
        for (int j = 0; j < 8; ++j) {
            int idx = e + j;
            int ic = idx < end ? idx : end - 1;
            s[j] = ss[ic];
            w[j] = idx < end ? sw[ic] : 0.f;
        }
        unsigned int g[8];
#pragma unroll
        for (int j = 0; j < 8; ++j) g[j] = hin[(size_t)s[j] * 64 + lane];
#pragma unroll
        for (int j = 0; j < 8; ++j) {
            ax = fmaf(w[j], __uint_as_float(g[j] << 16), ax);
            ay = fmaf(w[j], __uint_as_float(g[j] & 0xffff0000u), ay);
        }
    }
    if (OUTBF) {
        ((unsigned int*)hout)[(size_t)node * 64 + lane] = packbf2(ax, ay);
    } else {
        float2 o;
        o.x = ax;
        o.y = ay;
        ((float2*)hout)[(size_t)node * 64 + lane] = o;
    }
}

// ---------------- launch ----------------

extern "C" void kernel_launch(void* const* d_in, const int* in_sizes, int n_in,
                              void* d_out, int out_size, void* d_ws, size_t ws_size,
                              hipStream_t stream) {
    const float* x = (const float*)d_in[0];
    const float* W = (const float*)d_in[1];
    const float* b = (const float*)d_in[2];
    const int* esrc = (const int*)d_in[3];
    const int* edst = (const int*)d_in[4];
    const float* ew = (const float*)d_in[5];
    int N = in_sizes[0] / IN_DIM;
    int E = in_sizes[3];

    char* p = (char*)d_ws;
    auto alloc = [&](size_t bytes) -> void* {
        void* r = (void*)p;
        p += (bytes + 255) & ~(size_t)255;
        return r;
    };
    unsigned short* hbf = (unsigned short*)alloc((size_t)N * EMB * 2);
    unsigned short* h1bf = (unsigned short*)alloc((size_t)N * EMB * 2);
    unsigned short* wtg = (unsigned short*)alloc((size_t)IN_DIM * EMB * 2);
    int* deg = (int*)alloc((size_t)N * 4);
    int* row_ptr = (int*)alloc((size_t)(N + 1) * 4);
    int* cursor = (int*)alloc((size_t)N * 4);
    int* bsums = (int*)alloc(512);
    int* srt_src = (int*)alloc((size_t)E * 4);
    float* srt_w = (float*)alloc((size_t)E * 4);

    int nscan = (N + 1023) / 1024;  // 98 for N=100000 (must be <=128)

    wt_cast<<<(IN_DIM * EMB) / 256, 256, 0, stream>>>(W, wtg);
    hipMemsetAsync(deg, 0, (size_t)N * 4, stream);
    hist_kernel<<<(E + 255) / 256, 256, 0, stream>>>(edst, deg, E);
    scan_reduce<<<nscan, 256, 0, stream>>>(deg, bsums, N);
    scan_offsets<<<1, 128, 0, stream>>>(bsums, nscan, row_ptr, N, E);
    scan_write<<<nscan, 256, 0, stream>>>(deg, bsums, row_ptr, cursor, N);
    scatter_kernel<<<(E + 255) / 256, 256, 0, stream>>>(esrc, edst, ew, cursor, srt_src, srt_w, E);

    gemm_mfma<<<(N + 127) / 128, 256, 0, stream>>>(x, wtg, b, hbf, N);
    prop_g<1><<<(N + 3) / 4, 256, 0, stream>>>((const unsigned int*)hbf, h1bf, row_ptr, srt_src, srt_w, N);
    prop_g<0><<<(N + 3) / 4, 256, 0, stream>>>((const unsigned int*)h1bf, d_out, row_ptr, srt_src, srt_w, N);
}

// Round 3
// 303.996 us; speedup vs baseline: 2.0472x; 1.2535x over previous
//
#include <hip/hip_runtime.h>

#define IN_DIM 256
#define EMB 128
// bucket = dst >> 9 (512 nodes per bucket). Requires N <= 131072 (src packed in 17 bits).
#define BKT_SHIFT 9
#define BKT_NODES 512

typedef __attribute__((ext_vector_type(8))) short short8;
typedef __attribute__((ext_vector_type(4))) float f32x4;

__device__ __forceinline__ unsigned short bf16rtne(float f) {
    unsigned int u = __float_as_uint(f);
    return (unsigned short)((u + 0x7fffu + ((u >> 16) & 1u)) >> 16);
}

__device__ __forceinline__ unsigned int packbf2(float lo, float hi) {
    return ((unsigned int)bf16rtne(hi) << 16) | (unsigned int)bf16rtne(lo);
}

// ---------------- CSR build: bucket histogram ----------------

__global__ __launch_bounds__(256) void bucket_hist(const int* __restrict__ dst,
                                                   int* __restrict__ ghist, int E) {
    __shared__ int h[256];
    int t = threadIdx.x;
    h[t] = 0;
    __syncthreads();
    int e0 = blockIdx.x * 1024;
    int e1 = min(E, e0 + 1024);
    for (int i = e0 + t; i < e1; i += 256) atomicAdd(&h[dst[i] >> BKT_SHIFT], 1);
    __syncthreads();
    if (h[t]) atomicAdd(&ghist[t], h[t]);
}

// single block: exclusive scan of bucket counts -> bucket_off, gcursor
__global__ __launch_bounds__(256) void bucket_scan(const int* __restrict__ ghist,
                                                   int* __restrict__ bucket_off,
                                                   int* __restrict__ gcursor,
                                                   int* __restrict__ row_ptr,
                                                   int NB, int N, int E) {
    __shared__ int s[256];
    int t = threadIdx.x;
    int v = (t < NB) ? ghist[t] : 0;
    s[t] = v;
    __syncthreads();
    for (int off = 1; off < 256; off <<= 1) {
        int u = (t >= off) ? s[t - off] : 0;
        __syncthreads();
        s[t] += u;
        __syncthreads();
    }
    int excl = s[t] - v;
    if (t < NB) {
        bucket_off[t] = excl;
        gcursor[t] = excl;
    }
    if (t == 0) {
        bucket_off[NB] = E;
        row_ptr[N] = E;
    }
}

// ---------------- CSR build: bin edges by bucket (sequential-ish writes) ----------------

__global__ __launch_bounds__(256) void bin_scatter(const int* __restrict__ src,
                                                   const int* __restrict__ dst,
                                                   const float* __restrict__ w,
                                                   int* __restrict__ gcursor,
                                                   int2* __restrict__ binned, int E) {
    __shared__ int h[256];
    __shared__ int cur[256];
    int t = threadIdx.x;
    h[t] = 0;
    __syncthreads();
    int e0 = blockIdx.x * 4096;
    int e1 = min(E, e0 + 4096);
    for (int i = e0 + t; i < e1; i += 256) atomicAdd(&h[dst[i] >> BKT_SHIFT], 1);
    __syncthreads();
    cur[t] = h[t] ? atomicAdd(&gcursor[t], h[t]) : 0;
    __syncthreads();
    for (int i = e0 + t; i < e1; i += 256) {
        int d = dst[i];
        int b = d >> BKT_SHIFT;
        int ld = d & (BKT_NODES - 1);
        int pos = atomicAdd(&cur[b], 1);
        int2 r;
        r.x = src[i] | (ld << 17);
        r.y = __float_as_int(w[i]);
        binned[pos] = r;
    }
}

// ---------------- CSR build: per-bucket counting sort + row_ptr ----------------

__global__ __launch_bounds__(256) void bucket_sort(const int2* __restrict__ binned,
                                                   const int* __restrict__ bucket_off,
                                                   int2* __restrict__ sorted,
                                                   int* __restrict__ row_ptr, int N) {
    __shared__ int cnt[BKT_NODES];
    __shared__ int cur[BKT_NODES];
    __shared__ int scn[256];
    int t = threadIdx.x;
    int b = blockIdx.x;
    int node0 = b << BKT_SHIFT;
    int nn = min(BKT_NODES, N - node0);
    int beg = bucket_off[b];
    int endb = bucket_off[b + 1];
    cnt[t] = 0;
    cnt[t + 256] = 0;
    __syncthreads();
    for (int i = beg + t; i < endb; i += 256) {
        int ld = ((unsigned int)binned[i].x) >> 17;
        atomicAdd(&cnt[ld], 1);
    }
    __syncthreads();
    int a = cnt[2 * t];
    int b2 = cnt[2 * t + 1];
    scn[t] = a + b2;
    __syncthreads();
    for (int off = 1; off < 256; off <<= 1) {
        int u = (t >= off) ? scn[t - off] : 0;
        __syncthreads();
        scn[t] += u;
        __syncthreads();
    }
    int ep = scn[t] - (a + b2);
    int g0 = beg + ep;
    int g1 = g0 + a;
    cur[2 * t] = g0;
    cur[2 * t + 1] = g1;
    if (2 * t < nn) row_ptr[node0 + 2 * t] = g0;
    if (2 * t + 1 < nn) row_ptr[node0 + 2 * t + 1] = g1;
    __syncthreads();
    for (int i = beg + t; i < endb; i += 256) {
        int2 r = binned[i];
        int ld = ((unsigned int)r.x) >> 17;
        int pos = atomicAdd(&cur[ld], 1);
        r.x &= 0x1FFFF;
        sorted[pos] = r;
    }
}

// ---------------- W transpose + cast to bf16: wtg[c][k] = bf16(W[k][c]) ----------------

__global__ __launch_bounds__(256) void wt_cast(const float* __restrict__ W,
                                               unsigned short* __restrict__ wtg) {
    int i = blockIdx.x * 256 + threadIdx.x;  // 32768 total
    int c = i & 127;
    int k = i >> 7;
    wtg[c * 256 + k] = bf16rtne(W[(size_t)k * 128 + c]);
}

// ---------------- MFMA GEMM: h = relu(x@W + b), output bf16 ----------------

__global__ __launch_bounds__(256) void gemm_mfma(const float* __restrict__ x,
                                                 const unsigned short* __restrict__ wtg,
                                                 const float* __restrict__ bias,
                                                 unsigned short* __restrict__ hbf, int N) {
    __shared__ unsigned short xs[128][64];
    __shared__ unsigned short wsh[128][64];
    int tid = threadIdx.x;
    int row0 = blockIdx.x * 128;
    int wv = tid >> 6;
    int lane = tid & 63;
    int lr = lane & 15;
    int lg = lane >> 4;
    int wr = wv * 32;

    f32x4 acc[2][8];
#pragma unroll
    for (int m = 0; m < 2; ++m)
#pragma unroll
        for (int n = 0; n < 8; ++n) acc[m][n] = (f32x4){0.f, 0.f, 0.f, 0.f};

    int sr = tid >> 1;
    int hh = tid & 1;
    bool xvalid = (row0 + sr) < N;
    const float* xrow = x + (size_t)(row0 + sr) * IN_DIM + hh * 32;
    const unsigned short* wrow = wtg + (size_t)sr * IN_DIM + hh * 32;

    for (int kb = 0; kb < IN_DIM; kb += 64) {
#pragma unroll
        for (int j = 0; j < 4; ++j) {
            float4 f0 = make_float4(0.f, 0.f, 0.f, 0.f);
            float4 f1 = f0;
            if (xvalid) {
                f0 = ((const float4*)(xrow + kb))[2 * j];
                f1 = ((const float4*)(xrow + kb))[2 * j + 1];
            }
            uint4 pk;
            pk.x = packbf2(f0.x, f0.y);
            pk.y = packbf2(f0.z, f0.w);
            pk.z = packbf2(f1.x, f1.y);
            pk.w = packbf2(f1.z, f1.w);
            int koff = (hh * 32 + j * 8) ^ ((sr & 7) << 3);
            *(uint4*)&xs[sr][koff] = pk;
        }
#pragma unroll
        for (int j = 0; j < 4; ++j) {
            uint4 v = ((const uint4*)(wrow + kb))[j];
            int koff = (hh * 32 + j * 8) ^ ((sr & 7) << 3);
            *(uint4*)&wsh[sr][koff] = v;
        }
        __syncthreads();

        short8 a[2][2];
#pragma unroll
        for (int m = 0; m < 2; ++m)
#pragma unroll
            for (int kk = 0; kk < 2; ++kk) {
                int r = wr + m * 16 + lr;
                int koff = (kk * 32 + lg * 8) ^ ((lr & 7) << 3);
                a[m][kk] = *(const short8*)&xs[r][koff];
            }
#pragma unroll
        for (int n = 0; n < 8; ++n) {
            int c = n * 16 + lr;
            int koff0 = (lg * 8) ^ ((lr & 7) << 3);
            int koff1 = (32 + lg * 8) ^ ((lr & 7) << 3);
            short8 b0 = *(const short8*)&wsh[c][koff0];
            short8 b1 = *(const short8*)&wsh[c][koff1];
            acc[0][n] = __builtin_amdgcn_mfma_f32_16x16x32_bf16(a[0][0], b0, acc[0][n], 0, 0, 0);
            acc[0][n] = __builtin_amdgcn_mfma_f32_16x16x32_bf16(a[0][1], b1, acc[0][n], 0, 0, 0);
            acc[1][n] = __builtin_amdgcn_mfma_f32_16x16x32_bf16(a[1][0], b0, acc[1][n], 0, 0, 0);
            acc[1][n] = __builtin_amdgcn_mfma_f32_16x16x32_bf16(a[1][1], b1, acc[1][n], 0, 0, 0);
        }
        __syncthreads();
    }

#pragma unroll
    for (int n = 0; n < 8; ++n) {
        int c = n * 16 + lr;
        float bv = bias[c];
#pragma unroll
        for (int m = 0; m < 2; ++m) {
#pragma unroll
            for (int j = 0; j < 4; ++j) {
                int r = row0 + wr + m * 16 + lg * 4 + j;
                if (r < N) {
                    float v = fmaxf(acc[m][n][j] + bv, 0.f);
                    hbf[(size_t)r * EMB + c] = bf16rtne(v);
                }
            }
        }
    }
}

// ---------------- propagation: wave per node, 8-deep gather ILP, bf16 rows ----------------

template <int OUTBF>
__global__ __launch_bounds__(256) void prop_g(const unsigned int* __restrict__ hin,
                                              void* __restrict__ hout,
                                              const int* __restrict__ rp,
                                              const int2* __restrict__ rec, int N) {
    int wvid = threadIdx.x >> 6;
    int lane = threadIdx.x & 63;
    int node = blockIdx.x * 4 + wvid;
    if (node >= N) return;
    int beg = rp[node];
    int end = rp[node + 1];
    float ax = 0.f, ay = 0.f;
    for (int e = beg; e < end; e += 8) {
        int s[8];
        float w[8];
#pragma unroll
        for (int j = 0; j < 8; ++j) {
            int idx = e + j;
            int ic = idx < end ? idx : end - 1;
            int2 r = rec[ic];
            s[j] = r.x;
            w[j] = idx < end ? __int_as_float(r.y) : 0.f;
        }
        unsigned int g[8];
#pragma unroll
        for (int j = 0; j < 8; ++j) g[j] = hin[(size_t)s[j] * 64 + lane];
#pragma unroll
        for (int j = 0; j < 8; ++j) {
            ax = fmaf(w[j], __uint_as_float(g[j] << 16), ax);
            ay = fmaf(w[j], __uint_as_float(g[j] & 0xffff0000u), ay);
        }
    }
    if (OUTBF) {
        ((unsigned int*)hout)[(size_t)node * 64 + lane] = packbf2(ax, ay);
    } else {
        float2 o;
        o.x = ax;
        o.y = ay;
        ((float2*)hout)[(size_t)node * 64 + lane] = o;
    }
}

// ---------------- launch ----------------

extern "C" void kernel_launch(void* const* d_in, const int* in_sizes, int n_in,
                              void* d_out, int out_size, void* d_ws, size_t ws_size,
                              hipStream_t stream) {
    const float* x = (const float*)d_in[0];
    const float* W = (const float*)d_in[1];
    const float* b = (const float*)d_in[2];
    const int* esrc = (const int*)d_in[3];
    const int* edst = (const int*)d_in[4];
    const float* ew = (const float*)d_in[5];
    int N = in_sizes[0] / IN_DIM;
    int E = in_sizes[3];
    int NB = (N + BKT_NODES - 1) >> BKT_SHIFT;  // 196

    char* p = (char*)d_ws;
    auto alloc = [&](size_t bytes) -> void* {
        void* r = (void*)p;
        p += (bytes + 255) & ~(size_t)255;
        return r;
    };
    unsigned short* hbf = (unsigned short*)alloc((size_t)N * EMB * 2);
    unsigned short* h1bf = (unsigned short*)alloc((size_t)N * EMB * 2);
    unsigned short* wtg = (unsigned short*)alloc((size_t)IN_DIM * EMB * 2);
    int* ghist = (int*)alloc(256 * 4);
    int* gcursor = (int*)alloc(256 * 4);
    int* bucket_off = (int*)alloc((size_t)(NB + 1) * 4);
    int* row_ptr = (int*)alloc((size_t)(N + 1) * 4);
    int2* binned = (int2*)alloc((size_t)E * 8);
    int2* sorted = (int2*)alloc((size_t)E * 8);

    hipMemsetAsync(ghist, 0, 256 * 4, stream);
    bucket_hist<<<(E + 1023) / 1024, 256, 0, stream>>>(edst, ghist, E);
    bucket_scan<<<1, 256, 0, stream>>>(ghist, bucket_off, gcursor, row_ptr, NB, N, E);
    bin_scatter<<<(E + 4095) / 4096, 256, 0, stream>>>(esrc, edst, ew, gcursor, binned, E);
    bucket_sort<<<NB, 256, 0, stream>>>(binned, bucket_off, sorted, row_ptr, N);

    wt_cast<<<(IN_DIM * EMB) / 256, 256, 0, stream>>>(W, wtg);
    gemm_mfma<<<(N + 127) / 128, 256, 0, stream>>>(x, wtg, b, hbf, N);
    prop_g<1><<<(N + 3) / 4, 256, 0, stream>>>((const unsigned int*)hbf, h1bf, row_ptr, sorted, N);
    prop_g<0><<<(N + 3) / 4, 256, 0, stream>>>((const unsigned int*)h1bf, d_out, row_ptr, sorted, N);
}

// Round 4
// 250.797 us; speedup vs baseline: 2.4815x; 1.2121x over previous
//
#include <hip/hip_runtime.h>

#define IN_DIM 256
#define EMB 128
// bucket = dst >> 9 (512 nodes per bucket). Requires N <= 131072 (src packed in 17 bits).
#define BKT_SHIFT 9
#define BKT_NODES 512

typedef __attribute__((ext_vector_type(8))) short short8;
typedef __attribute__((ext_vector_type(4))) float f32x4;

__device__ __forceinline__ unsigned short bf16rtne(float f) {
    unsigned int u = __float_as_uint(f);
    return (unsigned short)((u + 0x7fffu + ((u >> 16) & 1u)) >> 16);
}

__device__ __forceinline__ unsigned int packbf2(float lo, float hi) {
    return ((unsigned int)bf16rtne(hi) << 16) | (unsigned int)bf16rtne(lo);
}

// ---------------- CSR build: bucket histogram ----------------

__global__ __launch_bounds__(256) void bucket_hist(const int* __restrict__ dst,
                                                   int* __restrict__ ghist, int E) {
    __shared__ int h[256];
    int t = threadIdx.x;
    h[t] = 0;
    __syncthreads();
    int e0 = blockIdx.x * 1024;
    int e1 = min(E, e0 + 1024);
    for (int i = e0 + t; i < e1; i += 256) atomicAdd(&h[dst[i] >> BKT_SHIFT], 1);
    __syncthreads();
    if (h[t]) atomicAdd(&ghist[t], h[t]);
}

// single block: exclusive scan of bucket counts -> bucket_off, gcursor
__global__ __launch_bounds__(256) void bucket_scan(const int* __restrict__ ghist,
                                                   int* __restrict__ bucket_off,
                                                   int* __restrict__ gcursor,
                                                   int* __restrict__ row_ptr,
                                                   int NB, int N, int E) {
    __shared__ int s[256];
    int t = threadIdx.x;
    int v = (t < NB) ? ghist[t] : 0;
    s[t] = v;
    __syncthreads();
    for (int off = 1; off < 256; off <<= 1) {
        int u = (t >= off) ? s[t - off] : 0;
        __syncthreads();
        s[t] += u;
        __syncthreads();
    }
    int excl = s[t] - v;
    if (t < NB) {
        bucket_off[t] = excl;
        gcursor[t] = excl;
    }
    if (t == 0) {
        bucket_off[NB] = E;
        row_ptr[N] = E;
    }
}

// ---------------- CSR build: bin edges by bucket (sequential-ish writes) ----------------

__global__ __launch_bounds__(512) void bin_scatter(const int* __restrict__ src,
                                                   const int* __restrict__ dst,
                                                   const float* __restrict__ w,
                                                   int* __restrict__ gcursor,
                                                   int2* __restrict__ binned, int E) {
    __shared__ int h[256];
    __shared__ int cur[256];
    int t = threadIdx.x;
    if (t < 256) h[t] = 0;
    __syncthreads();
    int e0 = blockIdx.x * 4096;
    int e1 = min(E, e0 + 4096);
    for (int i = e0 + t; i < e1; i += 512) atomicAdd(&h[dst[i] >> BKT_SHIFT], 1);
    __syncthreads();
    if (t < 256) cur[t] = h[t] ? atomicAdd(&gcursor[t], h[t]) : 0;
    __syncthreads();
    for (int i = e0 + t; i < e1; i += 512) {
        int d = dst[i];
        int b = d >> BKT_SHIFT;
        int ld = d & (BKT_NODES - 1);
        int pos = atomicAdd(&cur[b], 1);
        int2 r;
        r.x = src[i] | (ld << 17);
        r.y = __float_as_int(w[i]);
        binned[pos] = r;
    }
}

// ---------------- CSR build: per-bucket counting sort + row_ptr ----------------

__global__ __launch_bounds__(1024) void bucket_sort(const int2* __restrict__ binned,
                                                    const int* __restrict__ bucket_off,
                                                    int2* __restrict__ sorted,
                                                    int* __restrict__ row_ptr, int N) {
    __shared__ int cnt[BKT_NODES];
    __shared__ int cur[BKT_NODES];
    __shared__ int scn[BKT_NODES];
    int t = threadIdx.x;
    int b = blockIdx.x;
    int node0 = b << BKT_SHIFT;
    int nn = min(BKT_NODES, N - node0);
    int beg = bucket_off[b];
    int endb = bucket_off[b + 1];
    if (t < BKT_NODES) cnt[t] = 0;
    __syncthreads();
    for (int i = beg + t; i < endb; i += 1024) {
        int ld = ((unsigned int)binned[i].x) >> 17;
        atomicAdd(&cnt[ld], 1);
    }
    __syncthreads();
    int v = 0;
    if (t < BKT_NODES) {
        v = cnt[t];
        scn[t] = v;
    }
    __syncthreads();
    for (int off = 1; off < BKT_NODES; off <<= 1) {
        int u = 0;
        if (t < BKT_NODES && t >= off) u = scn[t - off];
        __syncthreads();
        if (t < BKT_NODES) scn[t] += u;
        __syncthreads();
    }
    if (t < BKT_NODES) {
        int ep = beg + scn[t] - v;  // exclusive start for local node t
        cur[t] = ep;
        if (t < nn) row_ptr[node0 + t] = ep;
    }
    __syncthreads();
    for (int i = beg + t; i < endb; i += 1024) {
        int2 r = binned[i];
        int ld = ((unsigned int)r.x) >> 17;
        int pos = atomicAdd(&cur[ld], 1);
        r.x &= 0x1FFFF;
        sorted[pos] = r;
    }
}

// ---------------- W transpose + cast to bf16: wtg[c][k] = bf16(W[k][c]) ----------------

__global__ __launch_bounds__(256) void wt_cast(const float* __restrict__ W,
                                               unsigned short* __restrict__ wtg) {
    int i = blockIdx.x * 256 + threadIdx.x;  // 32768 total
    int c = i & 127;
    int k = i >> 7;
    wtg[c * 256 + k] = bf16rtne(W[(size_t)k * 128 + c]);
}

// ---------------- MFMA GEMM: h = relu(x@W + b), output bf16 ----------------

__global__ __launch_bounds__(256) void gemm_mfma(const float* __restrict__ x,
                                                 const unsigned short* __restrict__ wtg,
                                                 const float* __restrict__ bias,
                                                 unsigned short* __restrict__ hbf, int N) {
    __shared__ unsigned short xs[128][64];
    __shared__ unsigned short wsh[128][64];
    int tid = threadIdx.x;
    int row0 = blockIdx.x * 128;
    int wv = tid >> 6;
    int lane = tid & 63;
    int lr = lane & 15;
    int lg = lane >> 4;
    int wr = wv * 32;

    f32x4 acc[2][8];
#pragma unroll
    for (int m = 0; m < 2; ++m)
#pragma unroll
        for (int n = 0; n < 8; ++n) acc[m][n] = (f32x4){0.f, 0.f, 0.f, 0.f};

    int sr = tid >> 1;
    int hh = tid & 1;
    bool xvalid = (row0 + sr) < N;
    const float* xrow = x + (size_t)(row0 + sr) * IN_DIM + hh * 32;
    const unsigned short* wrow = wtg + (size_t)sr * IN_DIM + hh * 32;

    for (int kb = 0; kb < IN_DIM; kb += 64) {
#pragma unroll
        for (int j = 0; j < 4; ++j) {
            float4 f0 = make_float4(0.f, 0.f, 0.f, 0.f);
            float4 f1 = f0;
            if (xvalid) {
                f0 = ((const float4*)(xrow + kb))[2 * j];
                f1 = ((const float4*)(xrow + kb))[2 * j + 1];
            }
            uint4 pk;
            pk.x = packbf2(f0.x, f0.y);
            pk.y = packbf2(f0.z, f0.w);
            pk.z = packbf2(f1.x, f1.y);
            pk.w = packbf2(f1.z, f1.w);
            int koff = (hh * 32 + j * 8) ^ ((sr & 7) << 3);
            *(uint4*)&xs[sr][koff] = pk;
        }
#pragma unroll
        for (int j = 0; j < 4; ++j) {
            uint4 v = ((const uint4*)(wrow + kb))[j];
            int koff = (hh * 32 + j * 8) ^ ((sr & 7) << 3);
            *(uint4*)&wsh[sr][koff] = v;
        }
        __syncthreads();

        short8 a[2][2];
#pragma unroll
        for (int m = 0; m < 2; ++m)
#pragma unroll
            for (int kk = 0; kk < 2; ++kk) {
                int r = wr + m * 16 + lr;
                int koff = (kk * 32 + lg * 8) ^ ((lr & 7) << 3);
                a[m][kk] = *(const short8*)&xs[r][koff];
            }
#pragma unroll
        for (int n = 0; n < 8; ++n) {
            int c = n * 16 + lr;
            int koff0 = (lg * 8) ^ ((lr & 7) << 3);
            int koff1 = (32 + lg * 8) ^ ((lr & 7) << 3);
            short8 b0 = *(const short8*)&wsh[c][koff0];
            short8 b1 = *(const short8*)&wsh[c][koff1];
            acc[0][n] = __builtin_amdgcn_mfma_f32_16x16x32_bf16(a[0][0], b0, acc[0][n], 0, 0, 0);
            acc[0][n] = __builtin_amdgcn_mfma_f32_16x16x32_bf16(a[0][1], b1, acc[0][n], 0, 0, 0);
            acc[1][n] = __builtin_amdgcn_mfma_f32_16x16x32_bf16(a[1][0], b0, acc[1][n], 0, 0, 0);
            acc[1][n] = __builtin_amdgcn_mfma_f32_16x16x32_bf16(a[1][1], b1, acc[1][n], 0, 0, 0);
        }
        __syncthreads();
    }

#pragma unroll
    for (int n = 0; n < 8; ++n) {
        int c = n * 16 + lr;
        float bv = bias[c];
#pragma unroll
        for (int m = 0; m < 2; ++m) {
#pragma unroll
            for (int j = 0; j < 4; ++j) {
                int r = row0 + wr + m * 16 + lg * 4 + j;
                if (r < N) {
                    float v = fmaxf(acc[m][n][j] + bv, 0.f);
                    hbf[(size_t)r * EMB + c] = bf16rtne(v);
                }
            }
        }
    }
}

// ---------------- propagation: wave per node ----------------
// One vector load grabs a chunk of up to 64 edge records; readlane broadcasts
// src/w to SGPRs so the gather is SGPR-base + lane offset and the clamp logic
// is uniform SALU. 8 gathers in flight per group.

template <int OUTBF>
__global__ __launch_bounds__(256) void prop_g(const unsigned int* __restrict__ hin,
                                              void* __restrict__ hout,
                                              const int* __restrict__ rp,
                                              const int2* __restrict__ rec, int N) {
    int wvid = threadIdx.x >> 6;
    int lane = threadIdx.x & 63;
    int node = blockIdx.x * 4 + wvid;
    if (node >= N) return;
    int beg = __builtin_amdgcn_readfirstlane(rp[node]);
    int end = __builtin_amdgcn_readfirstlane(rp[node + 1]);
    float ax = 0.f, ay = 0.f;
    for (int c0 = beg; c0 < end; c0 += 64) {
        int cnt = end - c0;
        if (cnt > 64) cnt = 64;
        int li = lane < cnt ? lane : 0;
        int2 r = rec[c0 + li];
        for (int jb = 0; jb < cnt; jb += 8) {
            int ssrc[8];
            float sw[8];
#pragma unroll
            for (int k = 0; k < 8; ++k) {
                int jj = jb + k;
                int jc = jj < cnt ? jj : 0;
                ssrc[k] = __builtin_amdgcn_readlane(r.x, jc);
                float wv = __uint_as_float((unsigned int)__builtin_amdgcn_readlane(r.y, jc));
                sw[k] = (jj < cnt) ? wv : 0.f;
            }
            unsigned int g[8];
#pragma unroll
            for (int k = 0; k < 8; ++k) g[k] = hin[(size_t)ssrc[k] * 64 + lane];
#pragma unroll
            for (int k = 0; k < 8; ++k) {
                ax = fmaf(sw[k], __uint_as_float(g[k] << 16), ax);
                ay = fmaf(sw[k], __uint_as_float(g[k] & 0xffff0000u), ay);
            }
        }
    }
    if (OUTBF) {
        ((unsigned int*)hout)[(size_t)node * 64 + lane] = packbf2(ax, ay);
    } else {
        float2 o;
        o.x = ax;
        o.y = ay;
        ((float2*)hout)[(size_t)node * 64 + lane] = o;
    }
}

// ---------------- launch ----------------

extern "C" void kernel_launch(void* const* d_in, const int* in_sizes, int n_in,
                              void* d_out, int out_size, void* d_ws, size_t ws_size,
                              hipStream_t stream) {
    const float* x = (const float*)d_in[0];
    const float* W = (const float*)d_in[1];
    const float* b = (const float*)d_in[2];
    const int* esrc = (const int*)d_in[3];
    const int* edst = (const int*)d_in[4];
    const float* ew = (const float*)d_in[5];
    int N = in_sizes[0] / IN_DIM;
    int E = in_sizes[3];
    int NB = (N + BKT_NODES - 1) >> BKT_SHIFT;  // 196

    char* p = (char*)d_ws;
    auto alloc = [&](size_t bytes) -> void* {
        void* r = (void*)p;
        p += (bytes + 255) & ~(size_t)255;
        return r;
    };
    unsigned short* hbf = (unsigned short*)alloc((size_t)N * EMB * 2);
    unsigned short* h1bf = (unsigned short*)alloc((size_t)N * EMB * 2);
    unsigned short* wtg = (unsigned short*)alloc((size_t)IN_DIM * EMB * 2);
    int* ghist = (int*)alloc(256 * 4);
    int* gcursor = (int*)alloc(256 * 4);
    int* bucket_off = (int*)alloc((size_t)(NB + 1) * 4);
    int* row_ptr = (int*)alloc((size_t)(N + 1) * 4);
    int2* binned = (int2*)alloc((size_t)E * 8);
    int2* sorted = (int2*)alloc((size_t)E * 8);

    hipMemsetAsync(ghist, 0, 256 * 4, stream);
    bucket_hist<<<(E + 1023) / 1024, 256, 0, stream>>>(edst, ghist, E);
    bucket_scan<<<1, 256, 0, stream>>>(ghist, bucket_off, gcursor, row_ptr, NB, N, E);
    bin_scatter<<<(E + 4095) / 4096, 512, 0, stream>>>(esrc, edst, ew, gcursor, binned, E);
    bucket_sort<<<NB, 1024, 0, stream>>>(binned, bucket_off, sorted, row_ptr, N);

    wt_cast<<<(IN_DIM * EMB) / 256, 256, 0, stream>>>(W, wtg);
    gemm_mfma<<<(N + 127) / 128, 256, 0, stream>>>(x, wtg, b, hbf, N);
    prop_g<1><<<(N + 3) / 4, 256, 0, stream>>>((const unsigned int*)hbf, h1bf, row_ptr, sorted, N);
    prop_g<0><<<(N + 3) / 4, 256, 0, stream>>>((const unsigned int*)h1bf, d_out, row_ptr, sorted, N);
}